// Round 19
// baseline (110.454 us; speedup 1.0000x reference)
//
#include <hip/hip_runtime.h>
#include <math.h>

#define HD 128
#define CAP 32       // bucket entries per node (u16); P(deg>32) ~ 1.6e-5
#define OVCAP 8192
#define NPROD 256    // pass-A producer blocks
#define PBCAP 64     // per-(block,bin) buffer entries
#define BINSZ 512    // nodes per bin
#define MAXBINS 112  // supports n_nodes <= 57344
#define NPB 16
#define RPT 8

typedef __attribute__((ext_vector_type(8))) short bf16x8;
typedef __attribute__((ext_vector_type(4))) float f32x4;

__device__ inline short f2bf(float x) {   // RTNE f32->bf16
    union { float f; unsigned u; } v; v.f = x;
    unsigned r = v.u + 0x7fff + ((v.u >> 16) & 1);
    return (short)(r >> 16);
}

#define LOG2E 1.4426950408889634f
#define LN2   0.6931471805599453f

__device__ inline float fast_sigmoid(float x) {
    return __builtin_amdgcn_rcpf(1.0f + __builtin_amdgcn_exp2f(-LOG2E * x));
}
__device__ inline float fast_softplus(float x) {
    float t = __builtin_amdgcn_exp2f(-LOG2E * fabsf(x));
    return fmaxf(x, 0.0f) + LN2 * __builtin_amdgcn_logf(1.0f + t);
}

// ---- prep0: zero overflow counters + build WtG ----
// WtG[j][k] = bf16(Wcat[k][j]), j in 0..255 (j<128: W1 col j; j>=128: W2 col j-128)

__global__ __launch_bounds__(256) void prep0(
    const float* __restrict__ W, short* __restrict__ WtG,
    int* __restrict__ ovA_cnt, int* __restrict__ ovB_cnt)
{
    const int tid = blockIdx.x * 256 + threadIdx.x;
    const int total = gridDim.x * 256;
    if (tid == 0) { *ovA_cnt = 0; *ovB_cnt = 0; }
    for (int i = tid; i < 256 * 128; i += total) {
        int j = i >> 7, k = i & 127;
        float w = (j < HD) ? W[k * HD + j] : W[(HD + k) * HD + (j - HD)];
        WtG[i] = f2bf(w);
    }
}

// ---- pass A: bin edges into block-private coalesced regions ----
__global__ __launch_bounds__(256) void partA(
    const int* __restrict__ src, const int* __restrict__ dst,
    unsigned* __restrict__ pb_buf,      // [NPROD][nbins][PBCAP]
    int* __restrict__ pb_cnt,           // [NPROD][nbins]
    unsigned* __restrict__ ovA, int* __restrict__ ovA_cnt,
    int n_edges, int nbins)
{
    __shared__ unsigned buf[MAXBINS][PBCAP];
    __shared__ int bcnt[MAXBINS];

    const int t = threadIdx.x;
    for (int i = t; i < nbins; i += 256) bcnt[i] = 0;
    __syncthreads();

    const int chunk = (n_edges + NPROD - 1) / NPROD;
    int e0 = blockIdx.x * chunk;
    int e1 = e0 + chunk; if (e1 > n_edges) e1 = n_edges;

    for (int e = e0 + t; e < e1; e += 256) {
        int d = dst[e], s = src[e];
        int bin = d >> 9;
        unsigned pk = ((unsigned)d << 16) | (unsigned)s;
        int pos = atomicAdd(&bcnt[bin], 1);
        if (pos < PBCAP) buf[bin][pos] = pk;
        else {
            int op = atomicAdd(ovA_cnt, 1);
            if (op < OVCAP) ovA[op] = pk;
        }
    }
    __syncthreads();

    // flattened, fully-parallel coalesced flush
    unsigned* myb = pb_buf + (size_t)blockIdx.x * nbins * PBCAP;
    int* myc = pb_cnt + (size_t)blockIdx.x * nbins;
    for (int i = t; i < nbins; i += 256) {
        int c = bcnt[i]; if (c > PBCAP) c = PBCAP;
        myc[i] = c;
    }
    const int tot = nbins * PBCAP;
    for (int idx = t; idx < tot; idx += 256) {
        int b = idx >> 6;        // PBCAP = 64
        int i = idx & 63;
        if (i < bcnt[b] && i < PBCAP) myb[idx] = buf[b][i];
    }
}

// ---- pass B: per-bin LDS bucket build (flattened consume) + coalesced write ----
__global__ __launch_bounds__(256) void partB(
    const unsigned* __restrict__ pb_buf, const int* __restrict__ pb_cnt,
    const unsigned* __restrict__ ovA, const int* __restrict__ ovA_cnt,
    unsigned* __restrict__ ovB, int* __restrict__ ovB_cnt,
    int* __restrict__ cnt, unsigned short* __restrict__ bkt,
    int n_nodes, int nbins)
{
    __shared__ unsigned short lbkt[BINSZ][CAP];   // 32 KB
    __shared__ int lcnt[BINSZ];                   // 2 KB
    __shared__ int scnt[NPROD];                   // 1 KB: this bin's per-producer counts

    const int t = threadIdx.x;
    const int bin = blockIdx.x;
    const int base = bin * BINSZ;

    for (int i = t; i < BINSZ; i += 256) lcnt[i] = 0;
    if (t < NPROD) scnt[t] = pb_cnt[(size_t)t * nbins + bin];
    __syncthreads();

    const int tot = NPROD * PBCAP;   // 16384
    for (int idx = t; idx < tot; idx += 256) {
        int p = idx >> 6;            // producer block
        int i = idx & 63;
        if (i < scnt[p]) {
            unsigned e = pb_buf[((size_t)p * nbins + bin) * PBCAP + i];
            int dl = (int)(e >> 16) - base;
            int pos = atomicAdd(&lcnt[dl], 1);
            if (pos < CAP) lbkt[dl][pos] = (unsigned short)(e & 0xffffu);
            else {
                int op = atomicAdd(ovB_cnt, 1);
                if (op < OVCAP) ovB[op] = e;
            }
        }
    }
    {   // producer-overflow entries for this bin (~never)
        int oc = *ovA_cnt; if (oc > OVCAP) oc = OVCAP;
        for (int i = t; i < oc; i += 256) {
            unsigned e = ovA[i];
            int d = (int)(e >> 16);
            if ((d >> 9) == bin) {
                int dl = d - base;
                int pos = atomicAdd(&lcnt[dl], 1);
                if (pos < CAP) lbkt[dl][pos] = (unsigned short)(e & 0xffffu);
                else {
                    int op = atomicAdd(ovB_cnt, 1);
                    if (op < OVCAP) ovB[op] = e;
                }
            }
        }
    }
    __syncthreads();

    for (int g0 = t; g0 < BINSZ; g0 += 256) {
        int g = base + g0;
        if (g < n_nodes) {
            cnt[g] = lcnt[g0];
            uint4* dstp = (uint4*)(bkt + (size_t)g * CAP);
            const uint4* srcp = (const uint4*)&lbkt[g0][0];
            dstp[0] = srcp[0];
            dstp[1] = srcp[1];
            dstp[2] = srcp[2];
            dstp[3] = srcp[3];
        }
    }
}

// ---- dense prep GEMM: m1b = bf16(h@W1), m2b = bf16(h@W2 + b) ----
// Block = 64 rows (4 tiles of 16), 4 waves: wave = (half, colhalf), 64 cols.
// B panel in registers; next tile's A-loads issued under current MFMAs.
// C-tiles staged in wave-private LDS -> coalesced 16B stores.
// A/B both use k = kf*32 + g*8 + slot; C/D: col=lane&15, row=(lane>>4)*4+reg.

__global__ __launch_bounds__(256) void prep_gemm(
    const float* __restrict__ h,     // [N][128] f32
    const short* __restrict__ WtG,   // [256][128] bf16
    const float* __restrict__ bias,  // [128] f32
    short* __restrict__ m1b,         // [N][128] bf16 out
    short* __restrict__ m2b,         // [N][128] bf16 out (h@W2 + b)
    int n_nodes)
{
    __shared__ short sb[2][2][16][72];   // [half][ch], padded

    const int lane = threadIdx.x & 63;
    const int wv = threadIdx.x >> 6;           // 0..3
    const int half = wv & 1;                   // 0: m1b, 1: m2b
    const int ch = wv >> 1;                    // col half
    const int c0 = ch * 64;
    const int row = lane & 15;
    const int g = lane >> 4;
    const int mBlk = blockIdx.x * 64;
    if (mBlk >= n_nodes) return;

    bf16x8 B[4][4];
    #pragma unroll
    for (int jt = 0; jt < 4; ++jt) {
        const short* wj = WtG + (size_t)(half * HD + c0 + jt * 16 + row) * HD + g * 8;
        #pragma unroll
        for (int kf = 0; kf < 4; ++kf)
            B[jt][kf] = *(const bf16x8*)(wj + kf * 32);
    }
    float bc[4];
    #pragma unroll
    for (int jt = 0; jt < 4; ++jt) bc[jt] = half ? bias[c0 + jt * 16 + row] : 0.f;

    short* const dstp = half ? m2b : m1b;

    float4 af[8];
    {
        int mA = mBlk + row; if (mA > n_nodes - 1) mA = n_nodes - 1;
        #pragma unroll
        for (int kf = 0; kf < 4; ++kf) {
            af[2 * kf]     = *(const float4*)(h + (size_t)mA * HD + kf * 32 + g * 8);
            af[2 * kf + 1] = *(const float4*)(h + (size_t)mA * HD + kf * 32 + g * 8 + 4);
        }
    }

    #pragma unroll
    for (int tt = 0; tt < 4; ++tt) {
        const int m0 = mBlk + tt * 16;

        bf16x8 a[4];
        #pragma unroll
        for (int kf = 0; kf < 4; ++kf) {
            float4 x = af[2 * kf], y = af[2 * kf + 1];
            bf16x8 tr = { f2bf(x.x), f2bf(x.y), f2bf(x.z), f2bf(x.w),
                          f2bf(y.x), f2bf(y.y), f2bf(y.z), f2bf(y.w) };
            a[kf] = tr;
        }
        if (tt < 3) {
            int mN = m0 + 16 + row; if (mN > n_nodes - 1) mN = n_nodes - 1;
            #pragma unroll
            for (int kf = 0; kf < 4; ++kf) {
                af[2 * kf]     = *(const float4*)(h + (size_t)mN * HD + kf * 32 + g * 8);
                af[2 * kf + 1] = *(const float4*)(h + (size_t)mN * HD + kf * 32 + g * 8 + 4);
            }
        }

        f32x4 acc[4];
        #pragma unroll
        for (int jt = 0; jt < 4; ++jt) acc[jt] = (f32x4){0.f, 0.f, 0.f, 0.f};
        #pragma unroll
        for (int jt = 0; jt < 4; ++jt)
            #pragma unroll
            for (int kf = 0; kf < 4; ++kf)
                acc[jt] = __builtin_amdgcn_mfma_f32_16x16x32_bf16(a[kf], B[jt][kf], acc[jt], 0, 0, 0);

        #pragma unroll
        for (int jt = 0; jt < 4; ++jt)
            #pragma unroll
            for (int r = 0; r < 4; ++r)
                sb[half][ch][g * 4 + r][jt * 16 + row] = f2bf(acc[jt][r] + bc[jt]);
        asm volatile("s_waitcnt lgkmcnt(0)" ::: "memory");
        #pragma unroll
        for (int ps = 0; ps < 2; ++ps) {
            int rr = ps * 8 + (lane >> 3);
            int c8 = lane & 7;
            int n = m0 + rr;
            bf16x8 v = *(const bf16x8*)&sb[half][ch][rr][c8 * 8];
            if (n < n_nodes)
                *(bf16x8*)(dstp + (size_t)n * HD + c0 + c8 * 8) = v;
        }
    }
}

// ---- gather + epilogue: ONE NODE PER WAVE (zero divergence) ----
// 64 lanes x 4B (2 bf16 cols) per edge row; predicated rolling unroll-8.
// out[n] = sigmoid(sum_e m1b[src] + deg*m2b[n]) + softplus(h[n])

__global__ __launch_bounds__(256) void gather_ep(
    const short* __restrict__ m1b, const int* __restrict__ cnt,
    const unsigned short* __restrict__ bkt,
    const unsigned* __restrict__ ov, const int* __restrict__ ov_cnt,
    const short* __restrict__ m2b,
    const float* __restrict__ h, float* __restrict__ out, int n_nodes)
{
    const int g = (blockIdx.x * 256 + threadIdx.x) >> 6;   // node = wave
    const int lane = threadIdx.x & 63;
    if (g >= n_nodes) return;
    const int degree = cnt[g];
    const int end = (degree < CAP) ? degree : CAP;
    const unsigned short* bl = bkt + (size_t)g * CAP;
    const int co = lane * 2;                                // 2 cols per lane

    float a0 = 0.f, a1 = 0.f, b0 = 0.f, b1 = 0.f;

    if (end > 0) {
        const int lastv = bl[end - 1];
        const uint4* bl4 = (const uint4*)bl;
        for (int base = 0; base < end; base += 8) {
            uint4 iv = bl4[base >> 3];
            int id8[8];
            id8[0] = iv.x & 0xffff; id8[1] = iv.x >> 16;
            id8[2] = iv.y & 0xffff; id8[3] = iv.y >> 16;
            id8[4] = iv.z & 0xffff; id8[5] = iv.z >> 16;
            id8[6] = iv.w & 0xffff; id8[7] = iv.w >> 16;
            #pragma unroll
            for (int j = 0; j < 8; ++j)
                if (base + j >= end) id8[j] = lastv;
            unsigned v[8];
            #pragma unroll
            for (int j = 0; j < 8; ++j)
                v[j] = *(const unsigned*)(m1b + (size_t)id8[j] * HD + co);
            #pragma unroll
            for (int j = 0; j < 8; ++j) {
                if (base + j < end) {
                    float lo = __uint_as_float(v[j] << 16);
                    float hi = __uint_as_float(v[j] & 0xffff0000u);
                    if (j & 1) { b0 += lo; b1 += hi; }
                    else       { a0 += lo; a1 += hi; }
                }
            }
        }
    }

    if (degree > CAP) {            // overflow list (~never taken)
        int oc = *ov_cnt; if (oc > OVCAP) oc = OVCAP;
        for (int i = 0; i < oc; ++i) {
            unsigned e = ov[i];
            if ((int)(e >> 16) == g) {
                unsigned vv = *(const unsigned*)(m1b + (size_t)(e & 0xffffu) * HD + co);
                a0 += __uint_as_float(vv << 16);
                a1 += __uint_as_float(vv & 0xffff0000u);
            }
        }
    }

    const float dg = (float)degree;
    unsigned mv = *(const unsigned*)(m2b + (size_t)g * HD + co);
    float m0 = __uint_as_float(mv << 16);
    float m1v = __uint_as_float(mv & 0xffff0000u);
    float2 hv = *(const float2*)(h + (size_t)g * HD + co);

    float o0 = fast_sigmoid((a0 + b0) + dg * m0)  + fast_softplus(hv.x);
    float o1 = fast_sigmoid((a1 + b1) + dg * m1v) + fast_softplus(hv.y);
    *(float2*)(out + (size_t)g * HD + co) = (float2){o0, o1};
}

// ================== fallback tiers ==================

__global__ __launch_bounds__(256) void zero_i32(int* __restrict__ p, int n)
{
    int i = blockIdx.x * 256 + threadIdx.x;
    if (i < n) p[i] = 0;
}

__global__ __launch_bounds__(256) void wt_convert(
    const float* __restrict__ W, short* __restrict__ Wt)
{
    int idx = blockIdx.x * 256 + threadIdx.x;
    int j = idx >> 8;
    int k = idx & 255;
    Wt[idx] = f2bf(W[k * HD + j]);
}

__global__ __launch_bounds__(256) void mpnn_scatter(
    const float* __restrict__ h, const int* __restrict__ src,
    const int* __restrict__ dst, float* __restrict__ S,
    int* __restrict__ deg, int n_edges)
{
    int gid = blockIdx.x * 256 + threadIdx.x;
    int e = gid >> 5;
    if (e >= n_edges) return;
    int lane = gid & 31;
    int s = src[e], d = dst[e];
    float4 v = *(const float4*)(h + (size_t)s * HD + lane * 4);
    float* srow = S + (size_t)d * HD + lane * 4;
    atomicAdd(srow + 0, v.x);
    atomicAdd(srow + 1, v.y);
    atomicAdd(srow + 2, v.z);
    atomicAdd(srow + 3, v.w);
    if (lane == 0) atomicAdd(deg + d, 1);
}

__global__ __launch_bounds__(256) void mpnn_node_mfma(
    const float* __restrict__ h,
    const short* __restrict__ Wt,    // [128][256]
    const float* __restrict__ bias,
    const int* __restrict__ deg,
    float* __restrict__ S,
    int n_nodes)
{
    const int lane = threadIdx.x & 63;
    const int wv = threadIdx.x >> 6;
    const int m0 = blockIdx.x * 32 + (wv >> 1) * 16;
    const int c0 = (wv & 1) * 64;
    if (m0 >= n_nodes) return;
    const int row = lane & 15;
    const int g = lane >> 4;

    const int nBase = m0 + g * 4;
    float dgO[4], hv[4][4], bc[4];
    #pragma unroll
    for (int r = 0; r < 4; ++r) {
        int n = nBase + r;
        int nc = (n < n_nodes) ? n : (n_nodes - 1);
        dgO[r] = (float)deg[nc];
        #pragma unroll
        for (int jt = 0; jt < 4; ++jt)
            hv[jt][r] = h[(size_t)nc * HD + c0 + jt * 16 + row];
    }
    #pragma unroll
    for (int jt = 0; jt < 4; ++jt) bc[jt] = bias[c0 + jt * 16 + row];

    int mA = m0 + row;
    if (mA > n_nodes - 1) mA = n_nodes - 1;
    const float dgA = (float)deg[mA];

    bf16x8 a[8];
    #pragma unroll
    for (int kf = 0; kf < 4; ++kf) {
        const float4* p = (const float4*)(S + (size_t)mA * HD + kf * 32 + g * 8);
        float4 x = p[0], y = p[1];
        bf16x8 t = { f2bf(x.x), f2bf(x.y), f2bf(x.z), f2bf(x.w),
                     f2bf(y.x), f2bf(y.y), f2bf(y.z), f2bf(y.w) };
        a[kf] = t;
    }
    #pragma unroll
    for (int kf = 0; kf < 4; ++kf) {
        const float4* p = (const float4*)(h + (size_t)mA * HD + kf * 32 + g * 8);
        float4 x = p[0], y = p[1];
        bf16x8 t = { f2bf(dgA * x.x), f2bf(dgA * x.y), f2bf(dgA * x.z), f2bf(dgA * x.w),
                     f2bf(dgA * y.x), f2bf(dgA * y.y), f2bf(dgA * y.z), f2bf(dgA * y.w) };
        a[4 + kf] = t;
    }

    f32x4 acc[4];
    #pragma unroll
    for (int jt = 0; jt < 4; ++jt) acc[jt] = (f32x4){0.f, 0.f, 0.f, 0.f};

    #pragma unroll
    for (int jt = 0; jt < 4; ++jt) {
        const short* wj = Wt + (size_t)(c0 + jt * 16 + row) * 256 + g * 8;
        #pragma unroll
        for (int kf = 0; kf < 8; ++kf) {
            bf16x8 bf = *(const bf16x8*)(wj + kf * 32);
            acc[jt] = __builtin_amdgcn_mfma_f32_16x16x32_bf16(a[kf], bf, acc[jt], 0, 0, 0);
        }
    }

    #pragma unroll
    for (int jt = 0; jt < 4; ++jt) {
        const int col = c0 + jt * 16 + row;
        #pragma unroll
        for (int r = 0; r < 4; ++r) {
            int n = nBase + r;
            if (n < n_nodes) {
                float agg = acc[jt][r] + dgO[r] * bc[jt];
                S[(size_t)n * HD + col] = fast_sigmoid(agg) + fast_softplus(hv[jt][r]);
            }
        }
    }
}

__global__ __launch_bounds__(256) void mpnn_node_f32(
    const float* __restrict__ h, const float* __restrict__ W,
    const float* __restrict__ b, const int* __restrict__ deg,
    float* __restrict__ S, int n_nodes)
{
    const int j = threadIdx.x & (HD - 1);
    const int g = threadIdx.x >> 7;
    const int n0 = blockIdx.x * NPB + g * RPT;

    float accS[RPT], accH[RPT];
    #pragma unroll
    for (int r = 0; r < RPT; ++r) { accS[r] = 0.f; accH[r] = 0.f; }

    int rmax = n_nodes - n0;
    if (rmax > RPT) rmax = RPT;
    if (rmax < 0) rmax = 0;

    for (int k = 0; k < HD; k += 4) {
        float w0 = W[(k + 0) * HD + j], w1 = W[(k + 1) * HD + j];
        float w2 = W[(k + 2) * HD + j], w3 = W[(k + 3) * HD + j];
        #pragma unroll
        for (int r = 0; r < RPT; ++r) if (r < rmax) {
            float4 a = *(const float4*)(S + (size_t)(n0 + r) * HD + k);
            accS[r] = fmaf(a.x, w0, fmaf(a.y, w1, fmaf(a.z, w2, fmaf(a.w, w3, accS[r]))));
        }
    }
    for (int k = 0; k < HD; k += 4) {
        float w0 = W[(HD + k + 0) * HD + j], w1 = W[(HD + k + 1) * HD + j];
        float w2 = W[(HD + k + 2) * HD + j], w3 = W[(HD + k + 3) * HD + j];
        #pragma unroll
        for (int r = 0; r < RPT; ++r) if (r < rmax) {
            float4 a = *(const float4*)(h + (size_t)(n0 + r) * HD + k);
            accH[r] = fmaf(a.x, w0, fmaf(a.y, w1, fmaf(a.z, w2, fmaf(a.w, w3, accH[r]))));
        }
    }
    __syncthreads();
    #pragma unroll
    for (int r = 0; r < RPT; ++r) if (r < rmax) {
        int n = n0 + r;
        float dg = (float)deg[n];
        float agg = accS[r] + dg * (accH[r] + b[j]);
        float hvv = h[(size_t)n * HD + j];
        S[(size_t)n * HD + j] = fast_sigmoid(agg) + fast_softplus(hvv);
    }
}

extern "C" void kernel_launch(void* const* d_in, const int* in_sizes, int n_in,
                              void* d_out, int out_size, void* d_ws, size_t ws_size,
                              hipStream_t stream)
{
    const float* h   = (const float*)d_in[0];
    const int*   src = (const int*)d_in[1];
    const int*   dst = (const int*)d_in[2];
    const float* W   = (const float*)d_in[3];
    const float* b   = (const float*)d_in[4];
    float* S = (float*)d_out;

    const int n_nodes = in_sizes[0] / HD;
    const int n_edges = in_sizes[1];
    const int WT_INTS = 2 * HD * HD / 2;
    const int nbins = (n_nodes + BINSZ - 1) / BINSZ;

    // ---- 16B-aligned ws layout (two-pass bucket path) ----
    char* p = (char*)d_ws;
    auto align16 = [](char* q) { return (char*)(((uintptr_t)q + 15) & ~(uintptr_t)15); };
    p = align16(p); int* cnt = (int*)p;                p += (size_t)n_nodes * 4;
    p = align16(p); unsigned short* bkt = (unsigned short*)p; p += (size_t)n_nodes * CAP * 2;
    p = align16(p); short* WtG = (short*)p;            p += (size_t)256 * HD * 2;
    p = align16(p); unsigned* pb_buf = (unsigned*)p;   p += (size_t)NPROD * nbins * PBCAP * 4;
    p = align16(p); int* pb_cnt = (int*)p;             p += (size_t)NPROD * nbins * 4;
    p = align16(p); unsigned* ovA = (unsigned*)p;      p += (size_t)OVCAP * 4;
    p = align16(p); unsigned* ovB = (unsigned*)p;      p += (size_t)OVCAP * 4;
    p = align16(p); int* ovA_cnt = (int*)p;            p += 16;
    p = align16(p); int* ovB_cnt = (int*)p;            p += 16;
    p = align16(p); short* m1b = (short*)p;            p += (size_t)n_nodes * HD * 2;
    p = align16(p); short* m2b = (short*)p;            p += (size_t)n_nodes * HD * 2;
    const size_t need_top = (size_t)(p - (char*)d_ws);

    const size_t need_mid = ((size_t)n_nodes + WT_INTS + 8) * sizeof(int);

    if (n_nodes <= BINSZ * MAXBINS && n_nodes <= 65535 && ws_size >= need_top) {
        prep0<<<128, 256, 0, stream>>>(W, WtG, ovA_cnt, ovB_cnt);

        partA<<<NPROD, 256, 0, stream>>>(src, dst, pb_buf, pb_cnt,
                                         ovA, ovA_cnt, n_edges, nbins);
        partB<<<nbins, 256, 0, stream>>>(pb_buf, pb_cnt, ovA, ovA_cnt,
                                         ovB, ovB_cnt, cnt, bkt, n_nodes, nbins);

        const int pblocks = (n_nodes + 63) / 64;
        prep_gemm<<<pblocks, 256, 0, stream>>>(h, WtG, b, m1b, m2b, n_nodes);

        const int gblocks = (int)(((long long)n_nodes * 64 + 255) / 256);
        gather_ep<<<gblocks, 256, 0, stream>>>(m1b, cnt, bkt, ovB, ovB_cnt,
                                               m2b, h, S, n_nodes);
    } else if (ws_size >= need_mid) {
        int* deg2  = (int*)d_ws;
        short* Wt2 = (short*)(deg2 + n_nodes);
        hipMemsetAsync(d_out, 0, (size_t)n_nodes * HD * sizeof(float), stream);
        zero_i32<<<(n_nodes + 255) / 256, 256, 0, stream>>>(deg2, n_nodes);
        wt_convert<<<(2 * HD * HD) / 256, 256, 0, stream>>>(W, Wt2);
        const int sblocks = (int)(((long long)n_edges * 32 + 255) / 256);
        mpnn_scatter<<<sblocks, 256, 0, stream>>>(h, src, dst, S, deg2, n_edges);
        const int mblocks = (n_nodes + 31) / 32;
        mpnn_node_mfma<<<mblocks, 256, 0, stream>>>(h, Wt2, b, deg2, S, n_nodes);
    } else {
        int* deg2 = (int*)d_ws;
        hipMemsetAsync(d_out, 0, (size_t)n_nodes * HD * sizeof(float), stream);
        zero_i32<<<(n_nodes + 255) / 256, 256, 0, stream>>>(deg2, n_nodes);
        const int sblocks = (int)(((long long)n_edges * 32 + 255) / 256);
        mpnn_scatter<<<sblocks, 256, 0, stream>>>(h, src, dst, S, deg2, n_edges);
        const int nblocks = (n_nodes + NPB - 1) / NPB;
        mpnn_node_f32<<<nblocks, 256, 0, stream>>>(h, W, b, deg2, S, n_nodes);
    }
}

// Round 20
// 110.081 us; speedup vs baseline: 1.0034x; 1.0034x over previous
//
#include <hip/hip_runtime.h>
#include <math.h>

#define HD 128
#define CAP 32       // bucket entries per node (u16); P(deg>32) ~ 1.6e-5
#define OVCAP 8192
#define NPROD 256    // pass-A producer blocks
#define PBCAP 64     // per-(block,bin) buffer entries
#define BINSZ 512    // nodes per bin
#define MAXBINS 112  // supports n_nodes <= 57344
#define NPB 16
#define RPT 8

typedef __attribute__((ext_vector_type(8))) short bf16x8;
typedef __attribute__((ext_vector_type(4))) float f32x4;

__device__ inline short f2bf(float x) {   // RTNE f32->bf16
    union { float f; unsigned u; } v; v.f = x;
    unsigned r = v.u + 0x7fff + ((v.u >> 16) & 1);
    return (short)(r >> 16);
}

#define LOG2E 1.4426950408889634f
#define LN2   0.6931471805599453f

__device__ inline float fast_sigmoid(float x) {
    return __builtin_amdgcn_rcpf(1.0f + __builtin_amdgcn_exp2f(-LOG2E * x));
}
__device__ inline float fast_softplus(float x) {
    float t = __builtin_amdgcn_exp2f(-LOG2E * fabsf(x));
    return fmaxf(x, 0.0f) + LN2 * __builtin_amdgcn_logf(1.0f + t);
}

__device__ inline void accum8(float* a, const uint4 u) {  // += 8 bf16 packed in uint4
    a[0] += __uint_as_float(u.x << 16);
    a[1] += __uint_as_float(u.x & 0xffff0000u);
    a[2] += __uint_as_float(u.y << 16);
    a[3] += __uint_as_float(u.y & 0xffff0000u);
    a[4] += __uint_as_float(u.z << 16);
    a[5] += __uint_as_float(u.z & 0xffff0000u);
    a[6] += __uint_as_float(u.w << 16);
    a[7] += __uint_as_float(u.w & 0xffff0000u);
}

// ---- prep0: zero overflow counters + build WtG ----
// WtG[j][k] = bf16(Wcat[k][j]), j in 0..255 (j<128: W1 col j; j>=128: W2 col j-128)

__global__ __launch_bounds__(256) void prep0(
    const float* __restrict__ W, short* __restrict__ WtG,
    int* __restrict__ ovA_cnt, int* __restrict__ ovB_cnt)
{
    const int tid = blockIdx.x * 256 + threadIdx.x;
    const int total = gridDim.x * 256;
    if (tid == 0) { *ovA_cnt = 0; *ovB_cnt = 0; }
    for (int i = tid; i < 256 * 128; i += total) {
        int j = i >> 7, k = i & 127;
        float w = (j < HD) ? W[k * HD + j] : W[(HD + k) * HD + (j - HD)];
        WtG[i] = f2bf(w);
    }
}

// ---- pass A: bin edges into block-private coalesced regions ----
__global__ __launch_bounds__(256) void partA(
    const int* __restrict__ src, const int* __restrict__ dst,
    unsigned* __restrict__ pb_buf,      // [NPROD][nbins][PBCAP]
    int* __restrict__ pb_cnt,           // [NPROD][nbins]
    unsigned* __restrict__ ovA, int* __restrict__ ovA_cnt,
    int n_edges, int nbins)
{
    __shared__ unsigned buf[MAXBINS][PBCAP];
    __shared__ int bcnt[MAXBINS];

    const int t = threadIdx.x;
    for (int i = t; i < nbins; i += 256) bcnt[i] = 0;
    __syncthreads();

    const int chunk = (n_edges + NPROD - 1) / NPROD;
    int e0 = blockIdx.x * chunk;
    int e1 = e0 + chunk; if (e1 > n_edges) e1 = n_edges;

    for (int e = e0 + t; e < e1; e += 256) {
        int d = dst[e], s = src[e];
        int bin = d >> 9;
        unsigned pk = ((unsigned)d << 16) | (unsigned)s;
        int pos = atomicAdd(&bcnt[bin], 1);
        if (pos < PBCAP) buf[bin][pos] = pk;
        else {
            int op = atomicAdd(ovA_cnt, 1);
            if (op < OVCAP) ovA[op] = pk;
        }
    }
    __syncthreads();

    // flattened, fully-parallel coalesced flush
    unsigned* myb = pb_buf + (size_t)blockIdx.x * nbins * PBCAP;
    int* myc = pb_cnt + (size_t)blockIdx.x * nbins;
    for (int i = t; i < nbins; i += 256) {
        int c = bcnt[i]; if (c > PBCAP) c = PBCAP;
        myc[i] = c;
    }
    const int tot = nbins * PBCAP;
    for (int idx = t; idx < tot; idx += 256) {
        int b = idx >> 6;        // PBCAP = 64
        int i = idx & 63;
        if (i < bcnt[b] && i < PBCAP) myb[idx] = buf[b][i];
    }
}

// ---- pass B: per-bin LDS bucket build (flattened consume) + coalesced write ----
__global__ __launch_bounds__(256) void partB(
    const unsigned* __restrict__ pb_buf, const int* __restrict__ pb_cnt,
    const unsigned* __restrict__ ovA, const int* __restrict__ ovA_cnt,
    unsigned* __restrict__ ovB, int* __restrict__ ovB_cnt,
    int* __restrict__ cnt, unsigned short* __restrict__ bkt,
    int n_nodes, int nbins)
{
    __shared__ unsigned short lbkt[BINSZ][CAP];   // 32 KB
    __shared__ int lcnt[BINSZ];                   // 2 KB
    __shared__ int scnt[NPROD];                   // 1 KB

    const int t = threadIdx.x;
    const int bin = blockIdx.x;
    const int base = bin * BINSZ;

    for (int i = t; i < BINSZ; i += 256) lcnt[i] = 0;
    if (t < NPROD) scnt[t] = pb_cnt[(size_t)t * nbins + bin];
    __syncthreads();

    const int tot = NPROD * PBCAP;   // 16384
    for (int idx = t; idx < tot; idx += 256) {
        int p = idx >> 6;            // producer block
        int i = idx & 63;
        if (i < scnt[p]) {
            unsigned e = pb_buf[((size_t)p * nbins + bin) * PBCAP + i];
            int dl = (int)(e >> 16) - base;
            int pos = atomicAdd(&lcnt[dl], 1);
            if (pos < CAP) lbkt[dl][pos] = (unsigned short)(e & 0xffffu);
            else {
                int op = atomicAdd(ovB_cnt, 1);
                if (op < OVCAP) ovB[op] = e;
            }
        }
    }
    {   // producer-overflow entries for this bin (~never)
        int oc = *ovA_cnt; if (oc > OVCAP) oc = OVCAP;
        for (int i = t; i < oc; i += 256) {
            unsigned e = ovA[i];
            int d = (int)(e >> 16);
            if ((d >> 9) == bin) {
                int dl = d - base;
                int pos = atomicAdd(&lcnt[dl], 1);
                if (pos < CAP) lbkt[dl][pos] = (unsigned short)(e & 0xffffu);
                else {
                    int op = atomicAdd(ovB_cnt, 1);
                    if (op < OVCAP) ovB[op] = e;
                }
            }
        }
    }
    __syncthreads();

    for (int g0 = t; g0 < BINSZ; g0 += 256) {
        int g = base + g0;
        if (g < n_nodes) {
            cnt[g] = lcnt[g0];
            uint4* dstp = (uint4*)(bkt + (size_t)g * CAP);
            const uint4* srcp = (const uint4*)&lbkt[g0][0];
            dstp[0] = srcp[0];
            dstp[1] = srcp[1];
            dstp[2] = srcp[2];
            dstp[3] = srcp[3];
        }
    }
}

// ---- dense prep GEMM: m1b = bf16(h@W1), m2b = bf16(h@W2 + b) ----
// Block = 64 rows (4 tiles of 16), 4 waves: wave = (half, colhalf), 64 cols.
// B panel in registers; next tile's A-loads issued under current MFMAs.
// C-tiles staged in wave-private LDS -> coalesced 16B stores.
// A/B both use k = kf*32 + g*8 + slot; C/D: col=lane&15, row=(lane>>4)*4+reg.

__global__ __launch_bounds__(256) void prep_gemm(
    const float* __restrict__ h,     // [N][128] f32
    const short* __restrict__ WtG,   // [256][128] bf16
    const float* __restrict__ bias,  // [128] f32
    short* __restrict__ m1b,         // [N][128] bf16 out
    short* __restrict__ m2b,         // [N][128] bf16 out (h@W2 + b)
    int n_nodes)
{
    __shared__ short sb[2][2][16][72];   // [half][ch], padded

    const int lane = threadIdx.x & 63;
    const int wv = threadIdx.x >> 6;           // 0..3
    const int half = wv & 1;                   // 0: m1b, 1: m2b
    const int ch = wv >> 1;                    // col half
    const int c0 = ch * 64;
    const int row = lane & 15;
    const int g = lane >> 4;
    const int mBlk = blockIdx.x * 64;
    if (mBlk >= n_nodes) return;

    bf16x8 B[4][4];
    #pragma unroll
    for (int jt = 0; jt < 4; ++jt) {
        const short* wj = WtG + (size_t)(half * HD + c0 + jt * 16 + row) * HD + g * 8;
        #pragma unroll
        for (int kf = 0; kf < 4; ++kf)
            B[jt][kf] = *(const bf16x8*)(wj + kf * 32);
    }
    float bc[4];
    #pragma unroll
    for (int jt = 0; jt < 4; ++jt) bc[jt] = half ? bias[c0 + jt * 16 + row] : 0.f;

    short* const dstp = half ? m2b : m1b;

    float4 af[8];
    {
        int mA = mBlk + row; if (mA > n_nodes - 1) mA = n_nodes - 1;
        #pragma unroll
        for (int kf = 0; kf < 4; ++kf) {
            af[2 * kf]     = *(const float4*)(h + (size_t)mA * HD + kf * 32 + g * 8);
            af[2 * kf + 1] = *(const float4*)(h + (size_t)mA * HD + kf * 32 + g * 8 + 4);
        }
    }

    #pragma unroll
    for (int tt = 0; tt < 4; ++tt) {
        const int m0 = mBlk + tt * 16;

        bf16x8 a[4];
        #pragma unroll
        for (int kf = 0; kf < 4; ++kf) {
            float4 x = af[2 * kf], y = af[2 * kf + 1];
            bf16x8 tr = { f2bf(x.x), f2bf(x.y), f2bf(x.z), f2bf(x.w),
                          f2bf(y.x), f2bf(y.y), f2bf(y.z), f2bf(y.w) };
            a[kf] = tr;
        }
        if (tt < 3) {
            int mN = m0 + 16 + row; if (mN > n_nodes - 1) mN = n_nodes - 1;
            #pragma unroll
            for (int kf = 0; kf < 4; ++kf) {
                af[2 * kf]     = *(const float4*)(h + (size_t)mN * HD + kf * 32 + g * 8);
                af[2 * kf + 1] = *(const float4*)(h + (size_t)mN * HD + kf * 32 + g * 8 + 4);
            }
        }

        f32x4 acc[4];
        #pragma unroll
        for (int jt = 0; jt < 4; ++jt) acc[jt] = (f32x4){0.f, 0.f, 0.f, 0.f};
        #pragma unroll
        for (int jt = 0; jt < 4; ++jt)
            #pragma unroll
            for (int kf = 0; kf < 4; ++kf)
                acc[jt] = __builtin_amdgcn_mfma_f32_16x16x32_bf16(a[kf], B[jt][kf], acc[jt], 0, 0, 0);

        #pragma unroll
        for (int jt = 0; jt < 4; ++jt)
            #pragma unroll
            for (int r = 0; r < 4; ++r)
                sb[half][ch][g * 4 + r][jt * 16 + row] = f2bf(acc[jt][r] + bc[jt]);
        asm volatile("s_waitcnt lgkmcnt(0)" ::: "memory");
        #pragma unroll
        for (int ps = 0; ps < 2; ++ps) {
            int rr = ps * 8 + (lane >> 3);
            int c8 = lane & 7;
            int n = m0 + rr;
            bf16x8 v = *(const bf16x8*)&sb[half][ch][rr][c8 * 8];
            if (n < n_nodes)
                *(bf16x8*)(dstp + (size_t)n * HD + c0 + c8 * 8) = v;
        }
    }
}

// ---- gather + epilogue (16 lanes/node, u16 bucket, 16B row reads) ----
// One wave-instruction moves 4 complete rows (4 groups x 16 lanes x 16B = 1KB).
// out[n] = sigmoid(sum_e m1b[src] + deg*m2b[n]) + softplus(h[n])

__global__ __launch_bounds__(256) void gather_ep(
    const short* __restrict__ m1b, const int* __restrict__ cnt,
    const unsigned short* __restrict__ bkt,
    const unsigned* __restrict__ ov, const int* __restrict__ ov_cnt,
    const short* __restrict__ m2b,
    const float* __restrict__ h, float* __restrict__ out, int n_nodes)
{
    int g = (blockIdx.x * 256 + threadIdx.x) >> 4;   // node
    int lane = threadIdx.x & 15;
    if (g >= n_nodes) return;
    const int degree = cnt[g];
    const int end = (degree < CAP) ? degree : CAP;
    const unsigned short* bl = bkt + (size_t)g * CAP;
    const size_t lo = (size_t)(lane * 8);

    float a0[8], a1[8];
    #pragma unroll
    for (int q = 0; q < 8; ++q) { a0[q] = 0.f; a1[q] = 0.f; }

    if (end > 0) {
        const int lastv = bl[end - 1];
        const uint4* bl4 = (const uint4*)bl;    // 8 u16 per uint4, row is 64B-aligned
        for (int base = 0; base < end; base += 8) {
            uint4 iv = bl4[base >> 3];
            int id8[8];
            id8[0] = iv.x & 0xffff; id8[1] = iv.x >> 16;
            id8[2] = iv.y & 0xffff; id8[3] = iv.y >> 16;
            id8[4] = iv.z & 0xffff; id8[5] = iv.z >> 16;
            id8[6] = iv.w & 0xffff; id8[7] = iv.w >> 16;
            #pragma unroll
            for (int j = 0; j < 8; ++j)
                if (base + j >= end) id8[j] = lastv;
            uint4 v[8];
            #pragma unroll
            for (int j = 0; j < 8; ++j)
                v[j] = *(const uint4*)(m1b + (size_t)id8[j] * HD + lo);
            #pragma unroll
            for (int j = 0; j < 8; ++j) {
                if (base + j < end) accum8((j & 1) ? a1 : a0, v[j]);
            }
        }
    }

    // overflow entries (deg > CAP): tiny packed list, ~never taken
    if (degree > CAP) {
        int oc = *ov_cnt; if (oc > OVCAP) oc = OVCAP;
        for (int i = 0; i < oc; ++i) {
            unsigned v = ov[i];
            if ((int)(v >> 16) == g) {
                uint4 vv = *(const uint4*)(m1b + (size_t)(v & 0xffffu) * HD + lo);
                accum8(a0, vv);
            }
        }
    }

    const float dg = (float)degree;
    uint4 mv = *(const uint4*)(m2b + (size_t)g * HD + lo);
    float mr[8];
    mr[0] = __uint_as_float(mv.x << 16); mr[1] = __uint_as_float(mv.x & 0xffff0000u);
    mr[2] = __uint_as_float(mv.y << 16); mr[3] = __uint_as_float(mv.y & 0xffff0000u);
    mr[4] = __uint_as_float(mv.z << 16); mr[5] = __uint_as_float(mv.z & 0xffff0000u);
    mr[6] = __uint_as_float(mv.w << 16); mr[7] = __uint_as_float(mv.w & 0xffff0000u);

    const float4* ph = (const float4*)(h + (size_t)g * HD + lo);
    float4 ha = ph[0], hb4 = ph[1];
    float hr[8] = { ha.x, ha.y, ha.z, ha.w, hb4.x, hb4.y, hb4.z, hb4.w };

    float o[8];
    #pragma unroll
    for (int q = 0; q < 8; ++q) {
        float agg = (a0[q] + a1[q]) + dg * mr[q];
        o[q] = fast_sigmoid(agg) + fast_softplus(hr[q]);
    }
    float4* po = (float4*)(out + (size_t)g * HD + lo);
    po[0] = (float4){o[0], o[1], o[2], o[3]};
    po[1] = (float4){o[4], o[5], o[6], o[7]};
}

// ================== fallback tiers ==================

__global__ __launch_bounds__(256) void zero_i32(int* __restrict__ p, int n)
{
    int i = blockIdx.x * 256 + threadIdx.x;
    if (i < n) p[i] = 0;
}

__global__ __launch_bounds__(256) void wt_convert(
    const float* __restrict__ W, short* __restrict__ Wt)
{
    int idx = blockIdx.x * 256 + threadIdx.x;
    int j = idx >> 8;
    int k = idx & 255;
    Wt[idx] = f2bf(W[k * HD + j]);
}

__global__ __launch_bounds__(256) void mpnn_scatter(
    const float* __restrict__ h, const int* __restrict__ src,
    const int* __restrict__ dst, float* __restrict__ S,
    int* __restrict__ deg, int n_edges)
{
    int gid = blockIdx.x * 256 + threadIdx.x;
    int e = gid >> 5;
    if (e >= n_edges) return;
    int lane = gid & 31;
    int s = src[e], d = dst[e];
    float4 v = *(const float4*)(h + (size_t)s * HD + lane * 4);
    float* srow = S + (size_t)d * HD + lane * 4;
    atomicAdd(srow + 0, v.x);
    atomicAdd(srow + 1, v.y);
    atomicAdd(srow + 2, v.z);
    atomicAdd(srow + 3, v.w);
    if (lane == 0) atomicAdd(deg + d, 1);
}

__global__ __launch_bounds__(256) void mpnn_node_mfma(
    const float* __restrict__ h,
    const short* __restrict__ Wt,    // [128][256]
    const float* __restrict__ bias,
    const int* __restrict__ deg,
    float* __restrict__ S,
    int n_nodes)
{
    const int lane = threadIdx.x & 63;
    const int wv = threadIdx.x >> 6;
    const int m0 = blockIdx.x * 32 + (wv >> 1) * 16;
    const int c0 = (wv & 1) * 64;
    if (m0 >= n_nodes) return;
    const int row = lane & 15;
    const int g = lane >> 4;

    const int nBase = m0 + g * 4;
    float dgO[4], hv[4][4], bc[4];
    #pragma unroll
    for (int r = 0; r < 4; ++r) {
        int n = nBase + r;
        int nc = (n < n_nodes) ? n : (n_nodes - 1);
        dgO[r] = (float)deg[nc];
        #pragma unroll
        for (int jt = 0; jt < 4; ++jt)
            hv[jt][r] = h[(size_t)nc * HD + c0 + jt * 16 + row];
    }
    #pragma unroll
    for (int jt = 0; jt < 4; ++jt) bc[jt] = bias[c0 + jt * 16 + row];

    int mA = m0 + row;
    if (mA > n_nodes - 1) mA = n_nodes - 1;
    const float dgA = (float)deg[mA];

    bf16x8 a[8];
    #pragma unroll
    for (int kf = 0; kf < 4; ++kf) {
        const float4* p = (const float4*)(S + (size_t)mA * HD + kf * 32 + g * 8);
        float4 x = p[0], y = p[1];
        bf16x8 t = { f2bf(x.x), f2bf(x.y), f2bf(x.z), f2bf(x.w),
                     f2bf(y.x), f2bf(y.y), f2bf(y.z), f2bf(y.w) };
        a[kf] = t;
    }
    #pragma unroll
    for (int kf = 0; kf < 4; ++kf) {
        const float4* p = (const float4*)(h + (size_t)mA * HD + kf * 32 + g * 8);
        float4 x = p[0], y = p[1];
        bf16x8 t = { f2bf(dgA * x.x), f2bf(dgA * x.y), f2bf(dgA * x.z), f2bf(dgA * x.w),
                     f2bf(dgA * y.x), f2bf(dgA * y.y), f2bf(dgA * y.z), f2bf(dgA * y.w) };
        a[4 + kf] = t;
    }

    f32x4 acc[4];
    #pragma unroll
    for (int jt = 0; jt < 4; ++jt) acc[jt] = (f32x4){0.f, 0.f, 0.f, 0.f};

    #pragma unroll
    for (int jt = 0; jt < 4; ++jt) {
        const short* wj = Wt + (size_t)(c0 + jt * 16 + row) * 256 + g * 8;
        #pragma unroll
        for (int kf = 0; kf < 8; ++kf) {
            bf16x8 bf = *(const bf16x8*)(wj + kf * 32);
            acc[jt] = __builtin_amdgcn_mfma_f32_16x16x32_bf16(a[kf], bf, acc[jt], 0, 0, 0);
        }
    }

    #pragma unroll
    for (int jt = 0; jt < 4; ++jt) {
        const int col = c0 + jt * 16 + row;
        #pragma unroll
        for (int r = 0; r < 4; ++r) {
            int n = nBase + r;
            if (n < n_nodes) {
                float agg = acc[jt][r] + dgO[r] * bc[jt];
                S[(size_t)n * HD + col] = fast_sigmoid(agg) + fast_softplus(hv[jt][r]);
            }
        }
    }
}

__global__ __launch_bounds__(256) void mpnn_node_f32(
    const float* __restrict__ h, const float* __restrict__ W,
    const float* __restrict__ b, const int* __restrict__ deg,
    float* __restrict__ S, int n_nodes)
{
    const int j = threadIdx.x & (HD - 1);
    const int g = threadIdx.x >> 7;
    const int n0 = blockIdx.x * NPB + g * RPT;

    float accS[RPT], accH[RPT];
    #pragma unroll
    for (int r = 0; r < RPT; ++r) { accS[r] = 0.f; accH[r] = 0.f; }

    int rmax = n_nodes - n0;
    if (rmax > RPT) rmax = RPT;
    if (rmax < 0) rmax = 0;

    for (int k = 0; k < HD; k += 4) {
        float w0 = W[(k + 0) * HD + j], w1 = W[(k + 1) * HD + j];
        float w2 = W[(k + 2) * HD + j], w3 = W[(k + 3) * HD + j];
        #pragma unroll
        for (int r = 0; r < RPT; ++r) if (r < rmax) {
            float4 a = *(const float4*)(S + (size_t)(n0 + r) * HD + k);
            accS[r] = fmaf(a.x, w0, fmaf(a.y, w1, fmaf(a.z, w2, fmaf(a.w, w3, accS[r]))));
        }
    }
    for (int k = 0; k < HD; k += 4) {
        float w0 = W[(HD + k + 0) * HD + j], w1 = W[(HD + k + 1) * HD + j];
        float w2 = W[(HD + k + 2) * HD + j], w3 = W[(HD + k + 3) * HD + j];
        #pragma unroll
        for (int r = 0; r < RPT; ++r) if (r < rmax) {
            float4 a = *(const float4*)(h + (size_t)(n0 + r) * HD + k);
            accH[r] = fmaf(a.x, w0, fmaf(a.y, w1, fmaf(a.z, w2, fmaf(a.w, w3, accH[r]))));
        }
    }
    __syncthreads();
    #pragma unroll
    for (int r = 0; r < RPT; ++r) if (r < rmax) {
        int n = n0 + r;
        float dg = (float)deg[n];
        float agg = accS[r] + dg * (accH[r] + b[j]);
        float hvv = h[(size_t)n * HD + j];
        S[(size_t)n * HD + j] = fast_sigmoid(agg) + fast_softplus(hvv);
    }
}

extern "C" void kernel_launch(void* const* d_in, const int* in_sizes, int n_in,
                              void* d_out, int out_size, void* d_ws, size_t ws_size,
                              hipStream_t stream)
{
    const float* h   = (const float*)d_in[0];
    const int*   src = (const int*)d_in[1];
    const int*   dst = (const int*)d_in[2];
    const float* W   = (const float*)d_in[3];
    const float* b   = (const float*)d_in[4];
    float* S = (float*)d_out;

    const int n_nodes = in_sizes[0] / HD;
    const int n_edges = in_sizes[1];
    const int WT_INTS = 2 * HD * HD / 2;
    const int nbins = (n_nodes + BINSZ - 1) / BINSZ;

    // ---- 16B-aligned ws layout (two-pass bucket path) ----
    char* p = (char*)d_ws;
    auto align16 = [](char* q) { return (char*)(((uintptr_t)q + 15) & ~(uintptr_t)15); };
    p = align16(p); int* cnt = (int*)p;                p += (size_t)n_nodes * 4;
    p = align16(p); unsigned short* bkt = (unsigned short*)p; p += (size_t)n_nodes * CAP * 2;
    p = align16(p); short* WtG = (short*)p;            p += (size_t)256 * HD * 2;
    p = align16(p); unsigned* pb_buf = (unsigned*)p;   p += (size_t)NPROD * nbins * PBCAP * 4;
    p = align16(p); int* pb_cnt = (int*)p;             p += (size_t)NPROD * nbins * 4;
    p = align16(p); unsigned* ovA = (unsigned*)p;      p += (size_t)OVCAP * 4;
    p = align16(p); unsigned* ovB = (unsigned*)p;      p += (size_t)OVCAP * 4;
    p = align16(p); int* ovA_cnt = (int*)p;            p += 16;
    p = align16(p); int* ovB_cnt = (int*)p;            p += 16;
    p = align16(p); short* m1b = (short*)p;            p += (size_t)n_nodes * HD * 2;
    p = align16(p); short* m2b = (short*)p;            p += (size_t)n_nodes * HD * 2;
    const size_t need_top = (size_t)(p - (char*)d_ws);

    const size_t need_mid = ((size_t)n_nodes + WT_INTS + 8) * sizeof(int);

    if (n_nodes <= BINSZ * MAXBINS && n_nodes <= 65535 && ws_size >= need_top) {
        prep0<<<128, 256, 0, stream>>>(W, WtG, ovA_cnt, ovB_cnt);

        partA<<<NPROD, 256, 0, stream>>>(src, dst, pb_buf, pb_cnt,
                                         ovA, ovA_cnt, n_edges, nbins);
        partB<<<nbins, 256, 0, stream>>>(pb_buf, pb_cnt, ovA, ovA_cnt,
                                         ovB, ovB_cnt, cnt, bkt, n_nodes, nbins);

        const int pblocks = (n_nodes + 63) / 64;
        prep_gemm<<<pblocks, 256, 0, stream>>>(h, WtG, b, m1b, m2b, n_nodes);

        const int gblocks = (int)(((long long)n_nodes * 16 + 255) / 256);
        gather_ep<<<gblocks, 256, 0, stream>>>(m1b, cnt, bkt, ovB, ovB_cnt,
                                               m2b, h, S, n_nodes);
    } else if (ws_size >= need_mid) {
        int* deg2  = (int*)d_ws;
        short* Wt2 = (short*)(deg2 + n_nodes);
        hipMemsetAsync(d_out, 0, (size_t)n_nodes * HD * sizeof(float), stream);
        zero_i32<<<(n_nodes + 255) / 256, 256, 0, stream>>>(deg2, n_nodes);
        wt_convert<<<(2 * HD * HD) / 256, 256, 0, stream>>>(W, Wt2);
        const int sblocks = (int)(((long long)n_edges * 32 + 255) / 256);
        mpnn_scatter<<<sblocks, 256, 0, stream>>>(h, src, dst, S, deg2, n_edges);
        const int mblocks = (n_nodes + 31) / 32;
        mpnn_node_mfma<<<mblocks, 256, 0, stream>>>(h, Wt2, b, deg2, S, n_nodes);
    } else {
        int* deg2 = (int*)d_ws;
        hipMemsetAsync(d_out, 0, (size_t)n_nodes * HD * sizeof(float), stream);
        zero_i32<<<(n_nodes + 255) / 256, 256, 0, stream>>>(deg2, n_nodes);
        const int sblocks = (int)(((long long)n_edges * 32 + 255) / 256);
        mpnn_scatter<<<sblocks, 256, 0, stream>>>(h, src, dst, S, deg2, n_edges);
        const int nblocks = (n_nodes + NPB - 1) / NPB;
        mpnn_node_f32<<<nblocks, 256, 0, stream>>>(h, W, b, deg2, S, n_nodes);
    }
}

// Round 21
// 99.191 us; speedup vs baseline: 1.1136x; 1.1098x over previous
//
#include <hip/hip_runtime.h>
#include <math.h>

#define HD 128
#define CAP 32       // bucket entries per node (u16); P(deg>32) ~ 1.6e-5
#define OVCAP 8192
#define NPROD 256    // pass-A producer blocks
#define PBCAP 64     // per-(block,bin) buffer entries
#define BINSZ 512    // nodes per bin
#define MAXBINS 112  // supports n_nodes <= 57344
#define NPB 16
#define RPT 8

typedef __attribute__((ext_vector_type(8))) short bf16x8;
typedef __attribute__((ext_vector_type(4))) float f32x4;

__device__ inline short f2bf(float x) {   // RTNE f32->bf16
    union { float f; unsigned u; } v; v.f = x;
    unsigned r = v.u + 0x7fff + ((v.u >> 16) & 1);
    return (short)(r >> 16);
}

#define LOG2E 1.4426950408889634f
#define LN2   0.6931471805599453f

__device__ inline float fast_sigmoid(float x) {
    return __builtin_amdgcn_rcpf(1.0f + __builtin_amdgcn_exp2f(-LOG2E * x));
}
__device__ inline float fast_softplus(float x) {
    float t = __builtin_amdgcn_exp2f(-LOG2E * fabsf(x));
    return fmaxf(x, 0.0f) + LN2 * __builtin_amdgcn_logf(1.0f + t);
}

__device__ inline void accum8(float* a, const uint4 u) {  // += 8 bf16 packed in uint4
    a[0] += __uint_as_float(u.x << 16);
    a[1] += __uint_as_float(u.x & 0xffff0000u);
    a[2] += __uint_as_float(u.y << 16);
    a[3] += __uint_as_float(u.y & 0xffff0000u);
    a[4] += __uint_as_float(u.z << 16);
    a[5] += __uint_as_float(u.z & 0xffff0000u);
    a[6] += __uint_as_float(u.w << 16);
    a[7] += __uint_as_float(u.w & 0xffff0000u);
}

// ---- prep0: zero overflow counters + build WtG ----
// WtG[j][k] = bf16(Wcat[k][j]), j in 0..255 (j<128: W1 col j; j>=128: W2 col j-128)

__global__ __launch_bounds__(256) void prep0(
    const float* __restrict__ W, short* __restrict__ WtG,
    int* __restrict__ ovA_cnt, int* __restrict__ ovB_cnt)
{
    const int tid = blockIdx.x * 256 + threadIdx.x;
    const int total = gridDim.x * 256;
    if (tid == 0) { *ovA_cnt = 0; *ovB_cnt = 0; }
    for (int i = tid; i < 256 * 128; i += total) {
        int j = i >> 7, k = i & 127;
        float w = (j < HD) ? W[k * HD + j] : W[(HD + k) * HD + (j - HD)];
        WtG[i] = f2bf(w);
    }
}

// ---- pass A: bin edges into block-private coalesced regions (R17 serial flush) ----
__global__ __launch_bounds__(256) void partA(
    const int* __restrict__ src, const int* __restrict__ dst,
    unsigned* __restrict__ pb_buf,      // [NPROD][nbins][PBCAP]
    int* __restrict__ pb_cnt,           // [NPROD][nbins]
    unsigned* __restrict__ ovA, int* __restrict__ ovA_cnt,
    int n_edges, int nbins)
{
    __shared__ unsigned buf[MAXBINS][PBCAP];
    __shared__ int bcnt[MAXBINS];

    const int t = threadIdx.x;
    for (int i = t; i < nbins; i += 256) bcnt[i] = 0;
    __syncthreads();

    const int chunk = (n_edges + NPROD - 1) / NPROD;
    int e0 = blockIdx.x * chunk;
    int e1 = e0 + chunk; if (e1 > n_edges) e1 = n_edges;

    for (int e = e0 + t; e < e1; e += 256) {
        int d = dst[e], s = src[e];
        int bin = d >> 9;
        unsigned pk = ((unsigned)d << 16) | (unsigned)s;
        int pos = atomicAdd(&bcnt[bin], 1);
        if (pos < PBCAP) buf[bin][pos] = pk;
        else {
            int op = atomicAdd(ovA_cnt, 1);
            if (op < OVCAP) ovA[op] = pk;
        }
    }
    __syncthreads();

    // coalesced flush of each bin buffer into this block's private region
    unsigned* myb = pb_buf + (size_t)blockIdx.x * nbins * PBCAP;
    int* myc = pb_cnt + (size_t)blockIdx.x * nbins;
    for (int b = 0; b < nbins; ++b) {
        int c = bcnt[b]; if (c > PBCAP) c = PBCAP;
        if (t < c) myb[(size_t)b * PBCAP + t] = buf[b][t];
        if (t == 0) myc[b] = c;
    }
}

// ---- pass B: per-bin LDS bucket build (R17 serial walk) + coalesced write ----
__global__ __launch_bounds__(256) void partB(
    const unsigned* __restrict__ pb_buf, const int* __restrict__ pb_cnt,
    const unsigned* __restrict__ ovA, const int* __restrict__ ovA_cnt,
    unsigned* __restrict__ ovB, int* __restrict__ ovB_cnt,
    int* __restrict__ cnt, unsigned short* __restrict__ bkt,
    int n_nodes, int nbins)
{
    __shared__ unsigned short lbkt[BINSZ][CAP];   // 32 KB
    __shared__ int lcnt[BINSZ];                   // 2 KB

    const int t = threadIdx.x;
    const int bin = blockIdx.x;
    const int base = bin * BINSZ;

    for (int i = t; i < BINSZ; i += 256) lcnt[i] = 0;
    __syncthreads();

    // consume this bin's segment from every producer (thread t = producer t)
    {
        int c = pb_cnt[(size_t)t * nbins + bin];
        const unsigned* seg = pb_buf + ((size_t)t * nbins + bin) * PBCAP;
        for (int i = 0; i < c; ++i) {
            unsigned e = seg[i];
            int dl = (int)(e >> 16) - base;
            int pos = atomicAdd(&lcnt[dl], 1);
            if (pos < CAP) lbkt[dl][pos] = (unsigned short)(e & 0xffffu);
            else {
                int op = atomicAdd(ovB_cnt, 1);
                if (op < OVCAP) ovB[op] = e;
            }
        }
    }
    // producer-overflow entries for this bin (~never)
    {
        int oc = *ovA_cnt; if (oc > OVCAP) oc = OVCAP;
        for (int i = t; i < oc; i += 256) {
            unsigned e = ovA[i];
            int d = (int)(e >> 16);
            if ((d >> 9) == bin) {
                int dl = d - base;
                int pos = atomicAdd(&lcnt[dl], 1);
                if (pos < CAP) lbkt[dl][pos] = (unsigned short)(e & 0xffffu);
                else {
                    int op = atomicAdd(ovB_cnt, 1);
                    if (op < OVCAP) ovB[op] = e;
                }
            }
        }
    }
    __syncthreads();

    // coalesced write-out: cnt + 64B bucket row per node
    for (int g0 = t; g0 < BINSZ; g0 += 256) {
        int g = base + g0;
        if (g < n_nodes) {
            cnt[g] = lcnt[g0];
            uint4* dstp = (uint4*)(bkt + (size_t)g * CAP);
            const uint4* srcp = (const uint4*)&lbkt[g0][0];
            dstp[0] = srcp[0];
            dstp[1] = srcp[1];
            dstp[2] = srcp[2];
            dstp[3] = srcp[3];
        }
    }
}

// ---- dense prep GEMM: m1b = bf16(h@W1), m2b = bf16(h@W2 + b) ----
// Block = 64 rows (4 tiles of 16), 4 waves: wave = (half, colhalf), 64 cols.
// B panel in registers; next tile's A-loads issued under current MFMAs.
// C-tiles staged in wave-private LDS -> coalesced 16B stores.
// A/B both use k = kf*32 + g*8 + slot; C/D: col=lane&15, row=(lane>>4)*4+reg.

__global__ __launch_bounds__(256) void prep_gemm(
    const float* __restrict__ h,     // [N][128] f32
    const short* __restrict__ WtG,   // [256][128] bf16
    const float* __restrict__ bias,  // [128] f32
    short* __restrict__ m1b,         // [N][128] bf16 out
    short* __restrict__ m2b,         // [N][128] bf16 out (h@W2 + b)
    int n_nodes)
{
    __shared__ short sb[2][2][16][72];   // [half][ch], padded

    const int lane = threadIdx.x & 63;
    const int wv = threadIdx.x >> 6;           // 0..3
    const int half = wv & 1;                   // 0: m1b, 1: m2b
    const int ch = wv >> 1;                    // col half
    const int c0 = ch * 64;
    const int row = lane & 15;
    const int g = lane >> 4;
    const int mBlk = blockIdx.x * 64;
    if (mBlk >= n_nodes) return;

    bf16x8 B[4][4];
    #pragma unroll
    for (int jt = 0; jt < 4; ++jt) {
        const short* wj = WtG + (size_t)(half * HD + c0 + jt * 16 + row) * HD + g * 8;
        #pragma unroll
        for (int kf = 0; kf < 4; ++kf)
            B[jt][kf] = *(const bf16x8*)(wj + kf * 32);
    }
    float bc[4];
    #pragma unroll
    for (int jt = 0; jt < 4; ++jt) bc[jt] = half ? bias[c0 + jt * 16 + row] : 0.f;

    short* const dstp = half ? m2b : m1b;

    float4 af[8];
    {
        int mA = mBlk + row; if (mA > n_nodes - 1) mA = n_nodes - 1;
        #pragma unroll
        for (int kf = 0; kf < 4; ++kf) {
            af[2 * kf]     = *(const float4*)(h + (size_t)mA * HD + kf * 32 + g * 8);
            af[2 * kf + 1] = *(const float4*)(h + (size_t)mA * HD + kf * 32 + g * 8 + 4);
        }
    }

    #pragma unroll
    for (int tt = 0; tt < 4; ++tt) {
        const int m0 = mBlk + tt * 16;

        bf16x8 a[4];
        #pragma unroll
        for (int kf = 0; kf < 4; ++kf) {
            float4 x = af[2 * kf], y = af[2 * kf + 1];
            bf16x8 tr = { f2bf(x.x), f2bf(x.y), f2bf(x.z), f2bf(x.w),
                          f2bf(y.x), f2bf(y.y), f2bf(y.z), f2bf(y.w) };
            a[kf] = tr;
        }
        if (tt < 3) {
            int mN = m0 + 16 + row; if (mN > n_nodes - 1) mN = n_nodes - 1;
            #pragma unroll
            for (int kf = 0; kf < 4; ++kf) {
                af[2 * kf]     = *(const float4*)(h + (size_t)mN * HD + kf * 32 + g * 8);
                af[2 * kf + 1] = *(const float4*)(h + (size_t)mN * HD + kf * 32 + g * 8 + 4);
            }
        }

        f32x4 acc[4];
        #pragma unroll
        for (int jt = 0; jt < 4; ++jt) acc[jt] = (f32x4){0.f, 0.f, 0.f, 0.f};
        #pragma unroll
        for (int jt = 0; jt < 4; ++jt)
            #pragma unroll
            for (int kf = 0; kf < 4; ++kf)
                acc[jt] = __builtin_amdgcn_mfma_f32_16x16x32_bf16(a[kf], B[jt][kf], acc[jt], 0, 0, 0);

        #pragma unroll
        for (int jt = 0; jt < 4; ++jt)
            #pragma unroll
            for (int r = 0; r < 4; ++r)
                sb[half][ch][g * 4 + r][jt * 16 + row] = f2bf(acc[jt][r] + bc[jt]);
        asm volatile("s_waitcnt lgkmcnt(0)" ::: "memory");
        #pragma unroll
        for (int ps = 0; ps < 2; ++ps) {
            int rr = ps * 8 + (lane >> 3);
            int c8 = lane & 7;
            int n = m0 + rr;
            bf16x8 v = *(const bf16x8*)&sb[half][ch][rr][c8 * 8];
            if (n < n_nodes)
                *(bf16x8*)(dstp + (size_t)n * HD + c0 + c8 * 8) = v;
        }
    }
}

// ---- gather + epilogue (16 lanes/node, u16 bucket, 16B row reads) ----
// One wave-instruction moves 4 complete rows (4 groups x 16 lanes x 16B = 1KB).
// out[n] = sigmoid(sum_e m1b[src] + deg*m2b[n]) + softplus(h[n])

__global__ __launch_bounds__(256) void gather_ep(
    const short* __restrict__ m1b, const int* __restrict__ cnt,
    const unsigned short* __restrict__ bkt,
    const unsigned* __restrict__ ov, const int* __restrict__ ov_cnt,
    const short* __restrict__ m2b,
    const float* __restrict__ h, float* __restrict__ out, int n_nodes)
{
    int g = (blockIdx.x * 256 + threadIdx.x) >> 4;   // node
    int lane = threadIdx.x & 15;
    if (g >= n_nodes) return;
    const int degree = cnt[g];
    const int end = (degree < CAP) ? degree : CAP;
    const unsigned short* bl = bkt + (size_t)g * CAP;
    const size_t lo = (size_t)(lane * 8);

    float a0[8], a1[8];
    #pragma unroll
    for (int q = 0; q < 8; ++q) { a0[q] = 0.f; a1[q] = 0.f; }

    if (end > 0) {
        const int lastv = bl[end - 1];
        const uint4* bl4 = (const uint4*)bl;    // 8 u16 per uint4, row is 64B-aligned
        for (int base = 0; base < end; base += 8) {
            uint4 iv = bl4[base >> 3];
            int id8[8];
            id8[0] = iv.x & 0xffff; id8[1] = iv.x >> 16;
            id8[2] = iv.y & 0xffff; id8[3] = iv.y >> 16;
            id8[4] = iv.z & 0xffff; id8[5] = iv.z >> 16;
            id8[6] = iv.w & 0xffff; id8[7] = iv.w >> 16;
            #pragma unroll
            for (int j = 0; j < 8; ++j)
                if (base + j >= end) id8[j] = lastv;
            uint4 v[8];
            #pragma unroll
            for (int j = 0; j < 8; ++j)
                v[j] = *(const uint4*)(m1b + (size_t)id8[j] * HD + lo);
            #pragma unroll
            for (int j = 0; j < 8; ++j) {
                if (base + j < end) accum8((j & 1) ? a1 : a0, v[j]);
            }
        }
    }

    // overflow entries (deg > CAP): tiny packed list, ~never taken
    if (degree > CAP) {
        int oc = *ov_cnt; if (oc > OVCAP) oc = OVCAP;
        for (int i = 0; i < oc; ++i) {
            unsigned v = ov[i];
            if ((int)(v >> 16) == g) {
                uint4 vv = *(const uint4*)(m1b + (size_t)(v & 0xffffu) * HD + lo);
                accum8(a0, vv);
            }
        }
    }

    const float dg = (float)degree;
    uint4 mv = *(const uint4*)(m2b + (size_t)g * HD + lo);
    float mr[8];
    mr[0] = __uint_as_float(mv.x << 16); mr[1] = __uint_as_float(mv.x & 0xffff0000u);
    mr[2] = __uint_as_float(mv.y << 16); mr[3] = __uint_as_float(mv.y & 0xffff0000u);
    mr[4] = __uint_as_float(mv.z << 16); mr[5] = __uint_as_float(mv.z & 0xffff0000u);
    mr[6] = __uint_as_float(mv.w << 16); mr[7] = __uint_as_float(mv.w & 0xffff0000u);

    const float4* ph = (const float4*)(h + (size_t)g * HD + lo);
    float4 ha = ph[0], hb4 = ph[1];
    float hr[8] = { ha.x, ha.y, ha.z, ha.w, hb4.x, hb4.y, hb4.z, hb4.w };

    float o[8];
    #pragma unroll
    for (int q = 0; q < 8; ++q) {
        float agg = (a0[q] + a1[q]) + dg * mr[q];
        o[q] = fast_sigmoid(agg) + fast_softplus(hr[q]);
    }
    float4* po = (float4*)(out + (size_t)g * HD + lo);
    po[0] = (float4){o[0], o[1], o[2], o[3]};
    po[1] = (float4){o[4], o[5], o[6], o[7]};
}

// ================== fallback tiers ==================

__global__ __launch_bounds__(256) void zero_i32(int* __restrict__ p, int n)
{
    int i = blockIdx.x * 256 + threadIdx.x;
    if (i < n) p[i] = 0;
}

__global__ __launch_bounds__(256) void wt_convert(
    const float* __restrict__ W, short* __restrict__ Wt)
{
    int idx = blockIdx.x * 256 + threadIdx.x;
    int j = idx >> 8;
    int k = idx & 255;
    Wt[idx] = f2bf(W[k * HD + j]);
}

__global__ __launch_bounds__(256) void mpnn_scatter(
    const float* __restrict__ h, const int* __restrict__ src,
    const int* __restrict__ dst, float* __restrict__ S,
    int* __restrict__ deg, int n_edges)
{
    int gid = blockIdx.x * 256 + threadIdx.x;
    int e = gid >> 5;
    if (e >= n_edges) return;
    int lane = gid & 31;
    int s = src[e], d = dst[e];
    float4 v = *(const float4*)(h + (size_t)s * HD + lane * 4);
    float* srow = S + (size_t)d * HD + lane * 4;
    atomicAdd(srow + 0, v.x);
    atomicAdd(srow + 1, v.y);
    atomicAdd(srow + 2, v.z);
    atomicAdd(srow + 3, v.w);
    if (lane == 0) atomicAdd(deg + d, 1);
}

__global__ __launch_bounds__(256) void mpnn_node_mfma(
    const float* __restrict__ h,
    const short* __restrict__ Wt,    // [128][256]
    const float* __restrict__ bias,
    const int* __restrict__ deg,
    float* __restrict__ S,
    int n_nodes)
{
    const int lane = threadIdx.x & 63;
    const int wv = threadIdx.x >> 6;
    const int m0 = blockIdx.x * 32 + (wv >> 1) * 16;
    const int c0 = (wv & 1) * 64;
    if (m0 >= n_nodes) return;
    const int row = lane & 15;
    const int g = lane >> 4;

    const int nBase = m0 + g * 4;
    float dgO[4], hv[4][4], bc[4];
    #pragma unroll
    for (int r = 0; r < 4; ++r) {
        int n = nBase + r;
        int nc = (n < n_nodes) ? n : (n_nodes - 1);
        dgO[r] = (float)deg[nc];
        #pragma unroll
        for (int jt = 0; jt < 4; ++jt)
            hv[jt][r] = h[(size_t)nc * HD + c0 + jt * 16 + row];
    }
    #pragma unroll
    for (int jt = 0; jt < 4; ++jt) bc[jt] = bias[c0 + jt * 16 + row];

    int mA = m0 + row;
    if (mA > n_nodes - 1) mA = n_nodes - 1;
    const float dgA = (float)deg[mA];

    bf16x8 a[8];
    #pragma unroll
    for (int kf = 0; kf < 4; ++kf) {
        const float4* p = (const float4*)(S + (size_t)mA * HD + kf * 32 + g * 8);
        float4 x = p[0], y = p[1];
        bf16x8 t = { f2bf(x.x), f2bf(x.y), f2bf(x.z), f2bf(x.w),
                     f2bf(y.x), f2bf(y.y), f2bf(y.z), f2bf(y.w) };
        a[kf] = t;
    }
    #pragma unroll
    for (int kf = 0; kf < 4; ++kf) {
        const float4* p = (const float4*)(h + (size_t)mA * HD + kf * 32 + g * 8);
        float4 x = p[0], y = p[1];
        bf16x8 t = { f2bf(dgA * x.x), f2bf(dgA * x.y), f2bf(dgA * x.z), f2bf(dgA * x.w),
                     f2bf(dgA * y.x), f2bf(dgA * y.y), f2bf(dgA * y.z), f2bf(dgA * y.w) };
        a[4 + kf] = t;
    }

    f32x4 acc[4];
    #pragma unroll
    for (int jt = 0; jt < 4; ++jt) acc[jt] = (f32x4){0.f, 0.f, 0.f, 0.f};

    #pragma unroll
    for (int jt = 0; jt < 4; ++jt) {
        const short* wj = Wt + (size_t)(c0 + jt * 16 + row) * 256 + g * 8;
        #pragma unroll
        for (int kf = 0; kf < 8; ++kf) {
            bf16x8 bf = *(const bf16x8*)(wj + kf * 32);
            acc[jt] = __builtin_amdgcn_mfma_f32_16x16x32_bf16(a[kf], bf, acc[jt], 0, 0, 0);
        }
    }

    #pragma unroll
    for (int jt = 0; jt < 4; ++jt) {
        const int col = c0 + jt * 16 + row;
        #pragma unroll
        for (int r = 0; r < 4; ++r) {
            int n = nBase + r;
            if (n < n_nodes) {
                float agg = acc[jt][r] + dgO[r] * bc[jt];
                S[(size_t)n * HD + col] = fast_sigmoid(agg) + fast_softplus(hv[jt][r]);
            }
        }
    }
}

__global__ __launch_bounds__(256) void mpnn_node_f32(
    const float* __restrict__ h, const float* __restrict__ W,
    const float* __restrict__ b, const int* __restrict__ deg,
    float* __restrict__ S, int n_nodes)
{
    const int j = threadIdx.x & (HD - 1);
    const int g = threadIdx.x >> 7;
    const int n0 = blockIdx.x * NPB + g * RPT;

    float accS[RPT], accH[RPT];
    #pragma unroll
    for (int r = 0; r < RPT; ++r) { accS[r] = 0.f; accH[r] = 0.f; }

    int rmax = n_nodes - n0;
    if (rmax > RPT) rmax = RPT;
    if (rmax < 0) rmax = 0;

    for (int k = 0; k < HD; k += 4) {
        float w0 = W[(k + 0) * HD + j], w1 = W[(k + 1) * HD + j];
        float w2 = W[(k + 2) * HD + j], w3 = W[(k + 3) * HD + j];
        #pragma unroll
        for (int r = 0; r < RPT; ++r) if (r < rmax) {
            float4 a = *(const float4*)(S + (size_t)(n0 + r) * HD + k);
            accS[r] = fmaf(a.x, w0, fmaf(a.y, w1, fmaf(a.z, w2, fmaf(a.w, w3, accS[r]))));
        }
    }
    for (int k = 0; k < HD; k += 4) {
        float w0 = W[(HD + k + 0) * HD + j], w1 = W[(HD + k + 1) * HD + j];
        float w2 = W[(HD + k + 2) * HD + j], w3 = W[(HD + k + 3) * HD + j];
        #pragma unroll
        for (int r = 0; r < RPT; ++r) if (r < rmax) {
            float4 a = *(const float4*)(h + (size_t)(n0 + r) * HD + k);
            accH[r] = fmaf(a.x, w0, fmaf(a.y, w1, fmaf(a.z, w2, fmaf(a.w, w3, accH[r]))));
        }
    }
    __syncthreads();
    #pragma unroll
    for (int r = 0; r < RPT; ++r) if (r < rmax) {
        int n = n0 + r;
        float dg = (float)deg[n];
        float agg = accS[r] + dg * (accH[r] + b[j]);
        float hvv = h[(size_t)n * HD + j];
        S[(size_t)n * HD + j] = fast_sigmoid(agg) + fast_softplus(hvv);
    }
}

extern "C" void kernel_launch(void* const* d_in, const int* in_sizes, int n_in,
                              void* d_out, int out_size, void* d_ws, size_t ws_size,
                              hipStream_t stream)
{
    const float* h   = (const float*)d_in[0];
    const int*   src = (const int*)d_in[1];
    const int*   dst = (const int*)d_in[2];
    const float* W   = (const float*)d_in[3];
    const float* b   = (const float*)d_in[4];
    float* S = (float*)d_out;

    const int n_nodes = in_sizes[0] / HD;
    const int n_edges = in_sizes[1];
    const int WT_INTS = 2 * HD * HD / 2;
    const int nbins = (n_nodes + BINSZ - 1) / BINSZ;

    // ---- 16B-aligned ws layout (two-pass bucket path) ----
    char* p = (char*)d_ws;
    auto align16 = [](char* q) { return (char*)(((uintptr_t)q + 15) & ~(uintptr_t)15); };
    p = align16(p); int* cnt = (int*)p;                p += (size_t)n_nodes * 4;
    p = align16(p); unsigned short* bkt = (unsigned short*)p; p += (size_t)n_nodes * CAP * 2;
    p = align16(p); short* WtG = (short*)p;            p += (size_t)256 * HD * 2;
    p = align16(p); unsigned* pb_buf = (unsigned*)p;   p += (size_t)NPROD * nbins * PBCAP * 4;
    p = align16(p); int* pb_cnt = (int*)p;             p += (size_t)NPROD * nbins * 4;
    p = align16(p); unsigned* ovA = (unsigned*)p;      p += (size_t)OVCAP * 4;
    p = align16(p); unsigned* ovB = (unsigned*)p;      p += (size_t)OVCAP * 4;
    p = align16(p); int* ovA_cnt = (int*)p;            p += 16;
    p = align16(p); int* ovB_cnt = (int*)p;            p += 16;
    p = align16(p); short* m1b = (short*)p;            p += (size_t)n_nodes * HD * 2;
    p = align16(p); short* m2b = (short*)p;            p += (size_t)n_nodes * HD * 2;
    const size_t need_top = (size_t)(p - (char*)d_ws);

    const size_t need_mid = ((size_t)n_nodes + WT_INTS + 8) * sizeof(int);

    if (n_nodes <= BINSZ * MAXBINS && n_nodes <= 65535 && ws_size >= need_top) {
        prep0<<<128, 256, 0, stream>>>(W, WtG, ovA_cnt, ovB_cnt);

        partA<<<NPROD, 256, 0, stream>>>(src, dst, pb_buf, pb_cnt,
                                         ovA, ovA_cnt, n_edges, nbins);
        partB<<<nbins, 256, 0, stream>>>(pb_buf, pb_cnt, ovA, ovA_cnt,
                                         ovB, ovB_cnt, cnt, bkt, n_nodes, nbins);

        const int pblocks = (n_nodes + 63) / 64;
        prep_gemm<<<pblocks, 256, 0, stream>>>(h, WtG, b, m1b, m2b, n_nodes);

        const int gblocks = (int)(((long long)n_nodes * 16 + 255) / 256);
        gather_ep<<<gblocks, 256, 0, stream>>>(m1b, cnt, bkt, ovB, ovB_cnt,
                                               m2b, h, S, n_nodes);
    } else if (ws_size >= need_mid) {
        int* deg2  = (int*)d_ws;
        short* Wt2 = (short*)(deg2 + n_nodes);
        hipMemsetAsync(d_out, 0, (size_t)n_nodes * HD * sizeof(float), stream);
        zero_i32<<<(n_nodes + 255) / 256, 256, 0, stream>>>(deg2, n_nodes);
        wt_convert<<<(2 * HD * HD) / 256, 256, 0, stream>>>(W, Wt2);
        const int sblocks = (int)(((long long)n_edges * 32 + 255) / 256);
        mpnn_scatter<<<sblocks, 256, 0, stream>>>(h, src, dst, S, deg2, n_edges);
        const int mblocks = (n_nodes + 31) / 32;
        mpnn_node_mfma<<<mblocks, 256, 0, stream>>>(h, Wt2, b, deg2, S, n_nodes);
    } else {
        int* deg2 = (int*)d_ws;
        hipMemsetAsync(d_out, 0, (size_t)n_nodes * HD * sizeof(float), stream);
        zero_i32<<<(n_nodes + 255) / 256, 256, 0, stream>>>(deg2, n_nodes);
        const int sblocks = (int)(((long long)n_edges * 32 + 255) / 256);
        mpnn_scatter<<<sblocks, 256, 0, stream>>>(h, src, dst, S, deg2, n_edges);
        const int nblocks = (n_nodes + NPB - 1) / NPB;
        mpnn_node_f32<<<nblocks, 256, 0, stream>>>(h, W, b, deg2, S, n_nodes);
    }
}